// Round 1
// baseline (500.990 us; speedup 1.0000x reference)
//
#include <hip/hip_runtime.h>
#include <math.h>

// Quantized ConvBlock, round 4: LDS-pipe attack on conv_main.
//   rocprof: conv_main was LDS-read-bound (54 ds_read_b128/wave/chunk = 3456 cy/CU-chunk
//   vs 1152 MFMA cy/SIMD; + 672 cy/CU-chunk bank conflicts from 32B lane stride).
//   Changes vs R3:
//     - wave tile 64o x (4 rows x 32 cols); kw-outer loop dedups row reads: 54 -> 36 reads/chunk.
//     - XOR bank swizzle (byte ^= ((idx>>2)&7)<<4) on xs and wl reads; write side handled by
//       per-lane pre-permuted global src for global_load_lds (xs) and pre-swizzled wq_b (wl).
//     - bijective XCD swizzle so o-blocks sharing an x-tile share an L2.
//
// ws layout (bytes):
//   0        : xmax bits (uint)             [memset to 0]
//   256      : fw[256] floats
//   2048     : wq_a  f16 [o][tap][c]        (fallback layout)
//   655360   : wq_b  f16 [cc][tap][o'][c16'] (bank-swizzled o/c-half slots)
//   2097152  : xq    f16 [n][cc][h][w][c16]

#define FW_NUM 20017.23017802413f
#define FX_NUM 835.5924988699913f
#define WQA_OFF 2048
#define WQB_OFF (640 * 1024)
#define XQ_OFF  (2 * 1024 * 1024)
#define XQ_BYTES 67108864ull

// fallback-kernel tile params (R2 kernel, kept verbatim)
#define CK  16
#define CKP 24
#define JW  130

typedef _Float16 half8 __attribute__((ext_vector_type(8)));
typedef _Float16 half4 __attribute__((ext_vector_type(4)));
typedef float floatx16 __attribute__((ext_vector_type(16)));

__device__ __forceinline__ void gl_lds16(const void* g, void* s) {
    __builtin_amdgcn_global_load_lds((const __attribute__((address_space(1))) void*)g,
                                     (__attribute__((address_space(3))) void*)s, 16, 0, 0);
}

__global__ void xmax_kernel(const float* __restrict__ x, unsigned int* wsu, int n4) {
    int tid = blockIdx.x * blockDim.x + threadIdx.x;
    int stride = gridDim.x * blockDim.x;
    const float4* x4 = (const float4*)x;
    float m = 0.f;
    for (int i = tid; i < n4; i += stride) {
        float4 v = x4[i];
        m = fmaxf(m, fmaxf(fmaxf(fabsf(v.x), fabsf(v.y)), fmaxf(fabsf(v.z), fabsf(v.w))));
    }
    #pragma unroll
    for (int off = 32; off >= 1; off >>= 1)
        m = fmaxf(m, __shfl_down(m, off, 64));
    __shared__ float sm[4];
    if ((threadIdx.x & 63) == 0) sm[threadIdx.x >> 6] = m;
    __syncthreads();
    if (threadIdx.x == 0) {
        m = fmaxf(fmaxf(sm[0], sm[1]), fmaxf(sm[2], sm[3]));
        atomicMax(wsu, __float_as_uint(m));
    }
}

// one block per o (256 blocks, 128 threads; t = input channel c)
__global__ void wq_kernel(const float* __restrict__ W, float* wsf, int big) {
    int o = blockIdx.x;
    int t = threadIdx.x;
    const float* wrow = W + o * 1152;
    float wv[9];
    float s = 0.f;
    #pragma unroll
    for (int k = 0; k < 9; k++) { wv[k] = wrow[t * 9 + k]; s += fabsf(wv[k]); }
    #pragma unroll
    for (int off = 32; off >= 1; off >>= 1) s += __shfl_down(s, off, 64);
    __shared__ float sred[2];
    __shared__ float sfw;
    if ((t & 63) == 0) sred[t >> 6] = s;
    __syncthreads();
    if (t == 0) {
        float wsum = sred[0] + sred[1];
        if (wsum == 0.f) wsum = 1.f;
        float fw = FW_NUM / wsum;
        wsf[64 + o] = fw;
        sfw = fw;
    }
    __syncthreads();
    float fw = sfw;
    _Float16* wqa = (_Float16*)((char*)wsf + WQA_OFF);   // [o][tap][c]
    _Float16* wqb = (_Float16*)((char*)wsf + WQB_OFF);   // [cc][tap][o'][c16'] swizzled slots
    // bank-swizzle slot for logical (o, half q): slot o' bits0-1 ^= o bits3-4, q' = q ^ o bit2
    int oswz = (o & ~3) | ((o & 3) ^ ((o >> 3) & 3));
    int qflip = (o >> 2) & 1;
    #pragma unroll
    for (int k = 0; k < 9; k++) {
        _Float16 hv = (_Float16)rintf(wv[k] * fw);       // rintf = RNE = jnp.round
        wqa[(o * 9 + k) * 128 + t] = hv;
        if (big) {
            int q = (t >> 3) & 1;
            int qswz = q ^ qflip;
            wqb[(((t >> 4) * 9 + k) * 256 + oswz) * 16 + qswz * 8 + (t & 7)] = hv;
        }
    }
}

// block = one (n, cc, h): quantize 16 c-planes' row h into [w][c16] (4 KB contiguous)
__global__ void quantx_kernel(const float* __restrict__ x, const float* __restrict__ wsf,
                              _Float16* __restrict__ xq) {
    int bid = blockIdx.x;           // (n*8 + cc)*128 + h
    int h  = bid & 127;
    int cc = (bid >> 7) & 7;
    int n  = bid >> 10;
    float xmax = __uint_as_float(((const unsigned int*)wsf)[0]);
    float fx = xmax > 0.f ? FX_NUM / xmax : 1.0f;
    int w = threadIdx.x;            // 128
    const float* xp = x + ((size_t)(n * 128 + cc * 16) * 128 + h) * 128 + w;
    half8 v0, v1;
    #pragma unroll
    for (int ci = 0; ci < 8; ci++)  v0[ci] = (_Float16)rintf(fx * xp[(size_t)ci * 16384]);
    #pragma unroll
    for (int ci = 8; ci < 16; ci++) v1[ci - 8] = (_Float16)rintf(fx * xp[(size_t)ci * 16384]);
    _Float16* op = xq + ((size_t)bid * 128 + w) * 16;
    *(half8*)op = v0;
    *(half8*)(op + 8) = v1;
}

__global__ __launch_bounds__(256, 2) void conv_main(const _Float16* __restrict__ xq,
                                                    const float* __restrict__ bias,
                                                    const float* __restrict__ wsf,
                                                    float* __restrict__ out) {
    // xs rows: r in 0..17 -> input h = h0 + r - 1;  cols j in 0..33 -> input w = w0 + j - 1
    // row stride 34*32 = 1088 B; pixel slot = 32 B, bank-swizzled within row.
    __shared__ __align__(16) _Float16 xs[2][18 * 34 * 16];   // 39168 B
    __shared__ __align__(16) _Float16 wl[2][9 * 64 * 16];    // 36864 B  [tap][o'][c16']
    __shared__ float sc[64], bz[64];                          // total 76544 B -> 2 blk/CU

    float xmax = __uint_as_float(((const unsigned int*)wsf)[0]);
    float fx = xmax > 0.f ? FX_NUM / xmax : 1.0f;

    // XCD-contiguous remap (2048 % 8 == 0 -> bijective): each XCD gets 2 images' full grid,
    // so the 4 o-blocks + neighboring h/w tiles sharing xq hit the same L2.
    int bx0 = blockIdx.x;
    int bx = (bx0 & 7) * 256 + (bx0 >> 3);
    int o0 = (bx & 3) << 6;
    int w0 = ((bx >> 2) & 3) << 5;
    int h0 = ((bx >> 4) & 7) << 4;
    int n  = bx >> 7;

    int tid = threadIdx.x;
    int lane = tid & 63;
    int wv = tid >> 6;
    int m32 = lane & 31;
    int q2 = lane >> 5;

    const char* wqb = (const char*)wsf + WQB_OFF;

    // ---- swizzled read column offsets (bytes within a row / tap block)
    int xcol[3];
    #pragma unroll
    for (int kw = 0; kw < 3; ++kw) {
        int j = m32 + kw;
        xcol[kw] = (j * 32 + q2 * 16) ^ ((((j) >> 2) & 7) << 4);
    }
    int wcol = (m32 * 32 + q2 * 16) ^ (((m32 >> 2) & 7) << 4);

    // ---- staging source permutation for xs: lane's linear LDS slot (jp,qp) -> occupant (j,q)
    int xsrcoff;
    {
        int jp = 1 + (lane >> 1), qp = lane & 1;
        int t = (jp >> 3) & 3;
        int j = (jp & ~3) | ((jp & 3) ^ t);
        int q = qp ^ ((jp >> 2) & 1);
        xsrcoff = (j - 1) * 32 + q * 16;   // bytes from pixel w0's data
    }

    // ---- init: zero both xs buffers (halo/OOB default), scale/bias to LDS
    {
        uint4 z = {0u, 0u, 0u, 0u};
        uint4* p = (uint4*)xs;
        for (int i = tid; i < (int)(sizeof(xs) / 16); i += 256) p[i] = z;
        if (tid < 64) {
            float fwv = wsf[64 + o0 + tid];
            sc[tid] = 1.0f / (fx * fwv);
            bz[tid] = bias[o0 + tid];
        }
    }
    __syncthreads();   // zero-fill visible before async writes land

    floatx16 acc[2][4];
    #pragma unroll
    for (int a1 = 0; a1 < 2; a1++)
        #pragma unroll
        for (int a2 = 0; a2 < 4; a2++)
            #pragma unroll
            for (int e = 0; e < 16; e++) acc[a1][a2][e] = 0.f;

    // ---- staging helpers: 18 x rows (1 KB each) + 18 w segs (9 taps x 2), 1 KB per wave-inst
    auto stage_async = [&](int ccs, int tb) {
        for (int s = wv; s < 36; s += 4) {
            if (s < 18) {
                int r = s;
                int h = h0 + r - 1;
                if (h >= 0 && h < 128) {
                    size_t pix = ((size_t)((n * 8 + ccs) * 128 + h)) * 128 + w0;
                    const char* src = (const char*)xq + pix * 32 + xsrcoff;   // per-lane permuted
                    char* dst = (char*)&xs[tb][(r * 34 + 1) * 16];            // linear, wave-uniform
                    gl_lds16(src, dst);
                }
            } else {
                int t2 = s - 18, tap = t2 >> 1, g = t2 & 1;
                const char* src = wqb + ((size_t)(ccs * 9 + tap) * 256 + o0) * 32 + g * 1024 + (size_t)lane * 16;
                char* dst = (char*)&wl[tb][tap * 64 * 16] + g * 1024;
                gl_lds16(src, dst);
            }
        }
    };
    // halo: 18 rows x 2 sides x 2 halves = 72 units; cols 0 and 33 are identity slots
    auto halo_load = [&](int ccs) -> half8 {
        half8 v = {};
        if (tid < 72) {
            int r = tid >> 2, sd = (tid >> 1) & 1, g = tid & 1;
            int h = h0 + r - 1;
            int wh = sd ? (w0 + 32) : (w0 - 1);
            if (h >= 0 && h < 128 && wh >= 0 && wh < 128)
                v = *(const half8*)(xq + (((size_t)((n * 8 + ccs) * 128 + h)) * 128 + wh) * 16 + g * 8);
        }
        return v;
    };
    auto halo_store = [&](int tb, half8 v) {
        if (tid < 72) {
            int r = tid >> 2, sd = (tid >> 1) & 1, g = tid & 1;
            int h = h0 + r - 1;
            int wh = sd ? (w0 + 32) : (w0 - 1);
            if (h >= 0 && h < 128 && wh >= 0 && wh < 128)
                *(half8*)((char*)&xs[tb][0] + r * 1088 + (sd ? 33 * 32 : 0) + g * 16) = v;
        }
    };

    // ---- prologue: chunk 0
    {
        half8 hv = halo_load(0);
        stage_async(0, 0);
        halo_store(0, hv);
    }
    __syncthreads();   // vmcnt(0)+lgkmcnt(0) drain: chunk 0 ready in buf 0

    // ---- K loop: 8 chunks of 16 c
    for (int cc = 0; cc < 8; ++cc) {
        int cb = cc & 1;
        half8 hn = {};
        if (cc < 7) {
            hn = halo_load(cc + 1);       // global->reg early (latency hidden by MFMA)
            stage_async(cc + 1, cb ^ 1);  // async global->LDS, other buffer
        }

        // MFMA on buffer cb: kw-outer dedups row reads (6 x-frags + 6 w-frags per kw)
        const char* xb = (const char*)&xs[cb][0] + wv * (4 * 1088);
        const char* wb = (const char*)&wl[cb][0];
        #pragma unroll
        for (int kw = 0; kw < 3; ++kw) {
            half8 xf[6];
            #pragma unroll
            for (int srow = 0; srow < 6; ++srow)
                xf[srow] = *(const half8*)(xb + srow * 1088 + xcol[kw]);
            #pragma unroll
            for (int kh = 0; kh < 3; ++kh) {
                const char* wp = wb + (kh * 3 + kw) * 2048 + wcol;
                half8 wf0 = *(const half8*)wp;
                half8 wf1 = *(const half8*)(wp + 1024);
                #pragma unroll
                for (int p = 0; p < 4; ++p) {
                    acc[0][p] = __builtin_amdgcn_mfma_f32_32x32x16_f16(wf0, xf[p + kh], acc[0][p], 0, 0, 0);
                    acc[1][p] = __builtin_amdgcn_mfma_f32_32x32x16_f16(wf1, xf[p + kh], acc[1][p], 0, 0, 0);
                }
            }
        }

        if (cc < 7) halo_store(cb ^ 1, hn);  // its vmcnt wait hides behind the barrier drain
        __syncthreads();
    }

    // ---- epilogue: D row = o (reg), col = pixel (lane) -> coalesced stores
    #pragma unroll
    for (int ot = 0; ot < 2; ++ot) {
        #pragma unroll
        for (int e = 0; e < 16; ++e) {
            int o_loc = ot * 32 + (e & 3) + 8 * (e >> 2) + 4 * q2;
            float scale = sc[o_loc];
            float bv = bz[o_loc];
            #pragma unroll
            for (int p = 0; p < 4; ++p) {
                int h = h0 + wv * 4 + p;
                float v = fmaxf(fmaf(acc[ot][p][e], scale, bv), 0.f);
                out[(((size_t)(n * 256 + o0 + o_loc)) * 128 + h) * 128 + w0 + m32] = v;
            }
        }
    }
}

// ---------------- fallback (R2 kernel, used if ws too small) ----------------
__global__ __launch_bounds__(256, 2) void conv_fallback(const float* __restrict__ x,
                                                        const float* __restrict__ bias,
                                                        const float* __restrict__ wsf,
                                                        float* __restrict__ out) {
    __shared__ __align__(16) _Float16 xs[6 * JW * CKP];
    __shared__ __align__(16) _Float16 wlds[9 * 64 * CKP];

    const unsigned int* wsu = (const unsigned int*)wsf;
    float xmax = __uint_as_float(wsu[0]);
    float fx = xmax > 0.f ? FX_NUM / xmax : 1.0f;

    int bx = blockIdx.x;
    int n  = bx >> 5;
    int h0 = (bx & 31) << 2;
    int o0 = blockIdx.y << 6;

    int tid  = threadIdx.x;
    int lane = tid & 63;
    int wave = tid >> 6;
    int m32  = lane & 31;
    int q2   = lane >> 5;

    const _Float16* wq16 = (const _Float16*)((const char*)wsf + WQA_OFF);
    const float* xn = x + (size_t)n * (128 * 128 * 128);

    floatx16 acc[4][2];
    #pragma unroll
    for (int mt = 0; mt < 4; mt++)
        #pragma unroll
        for (int nt = 0; nt < 2; nt++)
            #pragma unroll
            for (int e = 0; e < 16; e++) acc[mt][nt][e] = 0.f;

    if (tid < 192) {
        int r = tid >> 5;
        int s = tid & 31;
        int c = s & 15;
        int j = (s >> 4) ? (JW - 1) : 0;
        xs[(r * JW + j) * CKP + c] = (_Float16)0.f;
    }

    for (int c0 = 0; c0 < 128; c0 += CK) {
        __syncthreads();
        #pragma unroll
        for (int it = 0; it < 12; ++it) {
            int idx = tid + it * 256;
            int j  = (idx & 127) + 1;
            int c4 = (idx >> 7) & 3;
            int r  = idx >> 9;
            int h  = h0 + r - 1;
            float v0 = 0.f, v1 = 0.f, v2 = 0.f, v3 = 0.f;
            if (h >= 0 && h < 128) {
                const float* xp = xn + (size_t)(c0 + c4 * 4) * 16384 + h * 128 + (j - 1);
                v0 = xp[0]; v1 = xp[16384]; v2 = xp[32768]; v3 = xp[49152];
            }
            half4 hv;
            hv[0] = (_Float16)rintf(fx * v0);
            hv[1] = (_Float16)rintf(fx * v1);
            hv[2] = (_Float16)rintf(fx * v2);
            hv[3] = (_Float16)rintf(fx * v3);
            *(half4*)&xs[(r * JW + j) * CKP + c4 * 4] = hv;
        }
        #pragma unroll
        for (int it = 0; it < 5; ++it) {
            int idx = tid + it * 256;
            if (idx < 1152) {
                int o   = idx / 18;
                int rem = idx - o * 18;
                int tap = rem >> 1;
                int g   = rem & 1;
                half8 v = *(const half8*)(wq16 + ((size_t)(o0 + o) * 9 + tap) * 128 + c0 + g * 8);
                *(half8*)&wlds[(tap * 64 + o) * CKP + g * 8] = v;
            }
        }
        __syncthreads();

        const _Float16* xbase = &xs[(wave * JW + m32) * CKP + q2 * 8];
        const _Float16* wbase = &wlds[m32 * CKP + q2 * 8];
        #pragma unroll
        for (int kh = 0; kh < 3; ++kh) {
            #pragma unroll
            for (int kw = 0; kw < 3; ++kw) {
                int tap = kh * 3 + kw;
                half8 b0 = *(const half8*)(wbase + (tap * 64 +  0) * CKP);
                half8 b1 = *(const half8*)(wbase + (tap * 64 + 32) * CKP);
                #pragma unroll
                for (int mt = 0; mt < 4; ++mt) {
                    half8 a = *(const half8*)(xbase + (kh * JW + kw + mt * 32) * CKP);
                    acc[mt][0] = __builtin_amdgcn_mfma_f32_32x32x16_f16(a, b0, acc[mt][0], 0, 0, 0);
                    acc[mt][1] = __builtin_amdgcn_mfma_f32_32x32x16_f16(a, b1, acc[mt][1], 0, 0, 0);
                }
            }
        }
    }

    int h = h0 + wave;
    #pragma unroll
    for (int nt = 0; nt < 2; ++nt) {
        int o = o0 + nt * 32 + m32;
        float fwv = wsf[64 + o];
        float scale = 1.0f / (fx * fwv);
        float bv = bias[o];
        float* op = out + (((size_t)n * 256 + o) * 128 + h) * 128;
        #pragma unroll
        for (int mt = 0; mt < 4; ++mt) {
            #pragma unroll
            for (int g = 0; g < 4; ++g) {
                int w = mt * 32 + 8 * g + 4 * q2;
                float4 r;
                r.x = fmaxf(fmaf(acc[mt][nt][4 * g + 0], scale, bv), 0.f);
                r.y = fmaxf(fmaf(acc[mt][nt][4 * g + 1], scale, bv), 0.f);
                r.z = fmaxf(fmaf(acc[mt][nt][4 * g + 2], scale, bv), 0.f);
                r.w = fmaxf(fmaf(acc[mt][nt][4 * g + 3], scale, bv), 0.f);
                *(float4*)(op + w) = r;
            }
        }
    }
}

extern "C" void kernel_launch(void* const* d_in, const int* in_sizes, int n_in,
                              void* d_out, int out_size, void* d_ws, size_t ws_size,
                              hipStream_t stream) {
    const float* x = (const float*)d_in[0];   // [16,128,128,128]
    const float* W = (const float*)d_in[1];   // [256,128,3,3]
    const float* b = (const float*)d_in[2];   // [256]
    float* out = (float*)d_out;
    float* wsf = (float*)d_ws;

    int big = (ws_size >= (size_t)XQ_OFF + XQ_BYTES) ? 1 : 0;

    hipMemsetAsync(d_ws, 0, 256, stream);     // xmax slot (ws poisoned 0xAA)

    xmax_kernel<<<1024, 256, 0, stream>>>(x, (unsigned int*)d_ws, (16 * 128 * 128 * 128) / 4);
    wq_kernel<<<256, 128, 0, stream>>>(W, wsf, big);

    if (big) {
        _Float16* xq = (_Float16*)((char*)d_ws + XQ_OFF);
        quantx_kernel<<<16 * 8 * 128, 128, 0, stream>>>(x, wsf, xq);
        conv_main<<<2048, 256, 0, stream>>>(xq, b, wsf, out);
    } else {
        dim3 grid(512, 4);
        conv_fallback<<<grid, 256, 0, stream>>>(x, b, wsf, out);
    }
}

// Round 2
// 497.478 us; speedup vs baseline: 1.0071x; 1.0071x over previous
//
#include <hip/hip_runtime.h>
#include <math.h>

// Quantized ConvBlock, round 5: counted-vmcnt async pipeline (T4) for conv_main.
//   R1 analysis: per-CU-chunk MFMA 4608cy + LDS 3840cy + VALU 3000cy ran SERIALLY
//   (12.45k cy measured) because __syncthreads' full vmcnt(0) drain phase-locked all
//   waves. New structure per chunk:
//     s_barrier #1 (readers of other buffer done)
//     issue exactly 10 global_load_lds per wave (next chunk -> other buffer)
//     s_waitcnt vmcnt(10)   <- proves PREV chunk's staging retired; new loads stay in flight
//     s_barrier #2 (current buffer valid)  ->  compute (ds_read + MFMA, setprio on MFMA)
//   Staging is uniform: whole 34-px rows linear-filled with per-lane inverse-swizzled
//   sources; OOB rows/halo/dummy slots redirect to a zeroed scratch page (ZP) so the
//   per-wave load count is a compile-time constant. Halo reg-path removed.
//
// ws layout (bytes):
//   0        : xmax bits (uint)             [memset to 0]
//   256      : fw[256] floats
//   2048     : wq_a  f16 [o][tap][c]        (fallback layout)
//   655360   : wq_b  f16 [cc][tap][o'][c16'] (bank-swizzled slots)
//   1572864  : ZP zero page (2 KB, memset)
//   2097152  : xq    f16 [n][cc][h][w][c16]

#define FW_NUM 20017.23017802413f
#define FX_NUM 835.5924988699913f
#define WQA_OFF 2048
#define WQB_OFF (640 * 1024)
#define ZP_OFF  (1536 * 1024)
#define XQ_OFF  (2 * 1024 * 1024)
#define XQ_BYTES 67108864ull

// fallback-kernel tile params (R2 kernel, kept verbatim)
#define CK  16
#define CKP 24
#define JW  130

typedef _Float16 half8 __attribute__((ext_vector_type(8)));
typedef _Float16 half4 __attribute__((ext_vector_type(4)));
typedef float floatx16 __attribute__((ext_vector_type(16)));

__device__ __forceinline__ void gl_lds16(const void* g, void* s) {
    __builtin_amdgcn_global_load_lds((const __attribute__((address_space(1))) void*)g,
                                     (__attribute__((address_space(3))) void*)s, 16, 0, 0);
}

__global__ void xmax_kernel(const float* __restrict__ x, unsigned int* wsu, int n4) {
    int tid = blockIdx.x * blockDim.x + threadIdx.x;
    int stride = gridDim.x * blockDim.x;
    const float4* x4 = (const float4*)x;
    float m = 0.f;
    for (int i = tid; i < n4; i += stride) {
        float4 v = x4[i];
        m = fmaxf(m, fmaxf(fmaxf(fabsf(v.x), fabsf(v.y)), fmaxf(fabsf(v.z), fabsf(v.w))));
    }
    #pragma unroll
    for (int off = 32; off >= 1; off >>= 1)
        m = fmaxf(m, __shfl_down(m, off, 64));
    __shared__ float sm[4];
    if ((threadIdx.x & 63) == 0) sm[threadIdx.x >> 6] = m;
    __syncthreads();
    if (threadIdx.x == 0) {
        m = fmaxf(fmaxf(sm[0], sm[1]), fmaxf(sm[2], sm[3]));
        atomicMax(wsu, __float_as_uint(m));
    }
}

// one block per o (256 blocks, 128 threads; t = input channel c)
__global__ void wq_kernel(const float* __restrict__ W, float* wsf, int big) {
    int o = blockIdx.x;
    int t = threadIdx.x;
    const float* wrow = W + o * 1152;
    float wv[9];
    float s = 0.f;
    #pragma unroll
    for (int k = 0; k < 9; k++) { wv[k] = wrow[t * 9 + k]; s += fabsf(wv[k]); }
    #pragma unroll
    for (int off = 32; off >= 1; off >>= 1) s += __shfl_down(s, off, 64);
    __shared__ float sred[2];
    __shared__ float sfw;
    if ((t & 63) == 0) sred[t >> 6] = s;
    __syncthreads();
    if (t == 0) {
        float wsum = sred[0] + sred[1];
        if (wsum == 0.f) wsum = 1.f;
        float fw = FW_NUM / wsum;
        wsf[64 + o] = fw;
        sfw = fw;
    }
    __syncthreads();
    float fw = sfw;
    _Float16* wqa = (_Float16*)((char*)wsf + WQA_OFF);   // [o][tap][c]
    _Float16* wqb = (_Float16*)((char*)wsf + WQB_OFF);   // [cc][tap][o'][c16'] swizzled slots
    // bank-swizzle slot for logical (o, half q): slot o' bits0-1 ^= o bits3-4, q' = q ^ o bit2
    int oswz = (o & ~3) | ((o & 3) ^ ((o >> 3) & 3));
    int qflip = (o >> 2) & 1;
    #pragma unroll
    for (int k = 0; k < 9; k++) {
        _Float16 hv = (_Float16)rintf(wv[k] * fw);       // rintf = RNE = jnp.round
        wqa[(o * 9 + k) * 128 + t] = hv;
        if (big) {
            int q = (t >> 3) & 1;
            int qswz = q ^ qflip;
            wqb[(((t >> 4) * 9 + k) * 256 + oswz) * 16 + qswz * 8 + (t & 7)] = hv;
        }
    }
}

// block = one (n, cc, h): quantize 16 c-planes' row h into [w][c16] (4 KB contiguous)
__global__ void quantx_kernel(const float* __restrict__ x, const float* __restrict__ wsf,
                              _Float16* __restrict__ xq) {
    int bid = blockIdx.x;           // (n*8 + cc)*128 + h
    int h  = bid & 127;
    int cc = (bid >> 7) & 7;
    int n  = bid >> 10;
    float xmax = __uint_as_float(((const unsigned int*)wsf)[0]);
    float fx = xmax > 0.f ? FX_NUM / xmax : 1.0f;
    int w = threadIdx.x;            // 128
    const float* xp = x + ((size_t)(n * 128 + cc * 16) * 128 + h) * 128 + w;
    half8 v0, v1;
    #pragma unroll
    for (int ci = 0; ci < 8; ci++)  v0[ci] = (_Float16)rintf(fx * xp[(size_t)ci * 16384]);
    #pragma unroll
    for (int ci = 8; ci < 16; ci++) v1[ci - 8] = (_Float16)rintf(fx * xp[(size_t)ci * 16384]);
    _Float16* op = xq + ((size_t)bid * 128 + w) * 16;
    *(half8*)op = v0;
    *(half8*)(op + 8) = v1;
}

__global__ __launch_bounds__(256, 2) void conv_main(const _Float16* __restrict__ xq,
                                                    const float* __restrict__ bias,
                                                    const float* __restrict__ wsf,
                                                    float* __restrict__ out) {
    // xs: 18 rows x 68 slots(16B) = 19584 B + pad -> 20480 B per buffer.
    //   row r <-> input h = h0+r-1; slot sp occupant u = sp ^ ((sp>>3)&7), j=u>>1 (w=w0+j-1), q=u&1.
    // wl: 9 taps x 64 o x 32 B = 18432 B + 1024 pad -> 19456 B per buffer.
    __shared__ __align__(16) _Float16 xs[2][10240];   // 40960 B
    __shared__ __align__(16) _Float16 wl[2][9728];    // 38912 B
    __shared__ float sc[64], bz[64];                  // total 80384 B -> 2 blk/CU

    float xmax = __uint_as_float(((const unsigned int*)wsf)[0]);
    float fx = xmax > 0.f ? FX_NUM / xmax : 1.0f;

    // XCD-contiguous remap (2048 % 8 == 0 -> bijective)
    int bx0 = blockIdx.x;
    int bx = (bx0 & 7) * 256 + (bx0 >> 3);
    int o0 = (bx & 3) << 6;
    int w0 = ((bx >> 2) & 3) << 5;
    int h0 = ((bx >> 4) & 7) << 4;
    int n  = bx >> 7;

    int tid = threadIdx.x;
    int lane = tid & 63;
    int wv = tid >> 6;
    int m32 = lane & 31;
    int q2 = lane >> 5;

    const char* wsb = (const char*)wsf;

    // ---- swizzled read column offsets (bytes within a row / tap block)
    int xcol[3];
    #pragma unroll
    for (int kw = 0; kw < 3; ++kw) {
        int j = m32 + kw;
        xcol[kw] = (j * 32 + q2 * 16) ^ ((((j) >> 2) & 7) << 4);
    }
    int wcol = (m32 * 32 + q2 * 16) ^ (((m32 >> 2) & 7) << 4);

    // ---- per-wave staging slots: s = wv + 4k, k = 0..9 (40 slots: 20 x, 18 w, 2 dummy)
    //   sources as 32-bit offsets from ws base; OOB -> zero page; stride advances per chunk.
    int goff[10];
    int gstr[10];
    #pragma unroll
    for (int k = 0; k < 10; ++k) {
        int s = wv + 4 * k;
        int off, str;
        if (s < 20) {
            int slot = s * 64 + lane;
            int r = (slot * 241) >> 14;          // exact /68 for slot < 1224
            int spi = slot - r * 68;
            int u = spi ^ ((spi >> 3) & 7);      // involution: slot -> occupant
            int j = u >> 1, q = u & 1;
            int h = h0 + r - 1, w = w0 + j - 1;
            bool ok = (slot < 1224) && (h >= 0) && (h < 128) && (w >= 0) && (w < 128);
            if (ok) {
                off = XQ_OFF + n * 4194304 + (h * 128 + w) * 32 + q * 16;
                str = 524288;                    // next c-chunk plane
            } else {
                off = ZP_OFF + lane * 16;
                str = 0;
            }
        } else if (s < 38) {
            int t2 = s - 20, tap = t2 >> 1, g = t2 & 1;
            off = WQB_OFF + (tap * 256 + o0) * 32 + g * 1024 + lane * 16;
            str = 73728;                         // next c-chunk of wq_b
        } else {
            off = ZP_OFF + lane * 16;            // dummy (keeps vmcnt count uniform)
            str = 0;
        }
        goff[k] = off;
        gstr[k] = str;
    }

    auto stage = [&](int tb) {
        #pragma unroll
        for (int k = 0; k < 10; ++k) {
            int s = wv + 4 * k;
            char* dst;
            if (s < 20)      dst = (char*)&xs[tb][0] + s * 1024;
            else if (s < 38) dst = (char*)&wl[tb][0] + (s - 20) * 1024;
            else             dst = (char*)&wl[tb][0] + 18 * 1024;     // pad
            gl_lds16(wsb + goff[k], dst);
            goff[k] += gstr[k];
        }
    };

    // ---- init: scale/bias to LDS (before any staging; trivial drain)
    if (tid < 64) {
        float fwv = wsf[64 + o0 + tid];
        sc[tid] = 1.0f / (fx * fwv);
        bz[tid] = bias[o0 + tid];
    }
    __syncthreads();

    floatx16 acc[2][4];
    #pragma unroll
    for (int a1 = 0; a1 < 2; a1++)
        #pragma unroll
        for (int a2 = 0; a2 < 4; a2++)
            #pragma unroll
            for (int e = 0; e < 16; e++) acc[a1][a2][e] = 0.f;

    // ---- prologue: stage chunk 0 into buffer 0 (stays in flight through barrier #1)
    stage(0);

    // ---- K loop: 8 chunks of 16 c; 2 raw barriers, counted vmcnt, no full drain
    for (int cc = 0; cc < 8; ++cc) {
        int cb = cc & 1;
        __builtin_amdgcn_s_barrier();            // #1: all waves done reading buf cb^1
        if (cc < 7) {
            stage(cb ^ 1);                       // 10 loads: chunk cc+1 -> other buffer
            asm volatile("s_waitcnt vmcnt(10)" ::: "memory");   // chunk cc's loads retired
        } else {
            asm volatile("s_waitcnt vmcnt(0)" ::: "memory");
        }
        __builtin_amdgcn_s_barrier();            // #2: buf cb valid for everyone

        const char* xb = (const char*)&xs[cb][0] + wv * (4 * 1088);
        const char* wb = (const char*)&wl[cb][0];
        #pragma unroll
        for (int kw = 0; kw < 3; ++kw) {
            half8 xf[6];
            #pragma unroll
            for (int srow = 0; srow < 6; ++srow)
                xf[srow] = *(const half8*)(xb + srow * 1088 + xcol[kw]);
            #pragma unroll
            for (int kh = 0; kh < 3; ++kh) {
                const char* wp = wb + (kh * 3 + kw) * 2048 + wcol;
                half8 wf0 = *(const half8*)wp;
                half8 wf1 = *(const half8*)(wp + 1024);
                __builtin_amdgcn_s_setprio(1);
                #pragma unroll
                for (int p = 0; p < 4; ++p) {
                    acc[0][p] = __builtin_amdgcn_mfma_f32_32x32x16_f16(wf0, xf[p + kh], acc[0][p], 0, 0, 0);
                    acc[1][p] = __builtin_amdgcn_mfma_f32_32x32x16_f16(wf1, xf[p + kh], acc[1][p], 0, 0, 0);
                }
                __builtin_amdgcn_s_setprio(0);
            }
        }
    }

    // ---- epilogue: D row = o (reg), col = pixel (lane) -> coalesced stores
    #pragma unroll
    for (int ot = 0; ot < 2; ++ot) {
        #pragma unroll
        for (int e = 0; e < 16; ++e) {
            int o_loc = ot * 32 + (e & 3) + 8 * (e >> 2) + 4 * q2;
            float scale = sc[o_loc];
            float bv = bz[o_loc];
            #pragma unroll
            for (int p = 0; p < 4; ++p) {
                int h = h0 + wv * 4 + p;
                float v = fmaxf(fmaf(acc[ot][p][e], scale, bv), 0.f);
                out[(((size_t)(n * 256 + o0 + o_loc)) * 128 + h) * 128 + w0 + m32] = v;
            }
        }
    }
}

// ---------------- fallback (R2 kernel, used if ws too small) ----------------
__global__ __launch_bounds__(256, 2) void conv_fallback(const float* __restrict__ x,
                                                        const float* __restrict__ bias,
                                                        const float* __restrict__ wsf,
                                                        float* __restrict__ out) {
    __shared__ __align__(16) _Float16 xs[6 * JW * CKP];
    __shared__ __align__(16) _Float16 wlds[9 * 64 * CKP];

    const unsigned int* wsu = (const unsigned int*)wsf;
    float xmax = __uint_as_float(wsu[0]);
    float fx = xmax > 0.f ? FX_NUM / xmax : 1.0f;

    int bx = blockIdx.x;
    int n  = bx >> 5;
    int h0 = (bx & 31) << 2;
    int o0 = blockIdx.y << 6;

    int tid  = threadIdx.x;
    int lane = tid & 63;
    int wave = tid >> 6;
    int m32  = lane & 31;
    int q2   = lane >> 5;

    const _Float16* wq16 = (const _Float16*)((const char*)wsf + WQA_OFF);
    const float* xn = x + (size_t)n * (128 * 128 * 128);

    floatx16 acc[4][2];
    #pragma unroll
    for (int mt = 0; mt < 4; mt++)
        #pragma unroll
        for (int nt = 0; nt < 2; nt++)
            #pragma unroll
            for (int e = 0; e < 16; e++) acc[mt][nt][e] = 0.f;

    if (tid < 192) {
        int r = tid >> 5;
        int s = tid & 31;
        int c = s & 15;
        int j = (s >> 4) ? (JW - 1) : 0;
        xs[(r * JW + j) * CKP + c] = (_Float16)0.f;
    }

    for (int c0 = 0; c0 < 128; c0 += CK) {
        __syncthreads();
        #pragma unroll
        for (int it = 0; it < 12; ++it) {
            int idx = tid + it * 256;
            int j  = (idx & 127) + 1;
            int c4 = (idx >> 7) & 3;
            int r  = idx >> 9;
            int h  = h0 + r - 1;
            float v0 = 0.f, v1 = 0.f, v2 = 0.f, v3 = 0.f;
            if (h >= 0 && h < 128) {
                const float* xp = xn + (size_t)(c0 + c4 * 4) * 16384 + h * 128 + (j - 1);
                v0 = xp[0]; v1 = xp[16384]; v2 = xp[32768]; v3 = xp[49152];
            }
            half4 hv;
            hv[0] = (_Float16)rintf(fx * v0);
            hv[1] = (_Float16)rintf(fx * v1);
            hv[2] = (_Float16)rintf(fx * v2);
            hv[3] = (_Float16)rintf(fx * v3);
            *(half4*)&xs[(r * JW + j) * CKP + c4 * 4] = hv;
        }
        #pragma unroll
        for (int it = 0; it < 5; ++it) {
            int idx = tid + it * 256;
            if (idx < 1152) {
                int o   = idx / 18;
                int rem = idx - o * 18;
                int tap = rem >> 1;
                int g   = rem & 1;
                half8 v = *(const half8*)(wq16 + ((size_t)(o0 + o) * 9 + tap) * 128 + c0 + g * 8);
                *(half8*)&wlds[(tap * 64 + o) * CKP + g * 8] = v;
            }
        }
        __syncthreads();

        const _Float16* xbase = &xs[(wave * JW + m32) * CKP + q2 * 8];
        const _Float16* wbase = &wlds[m32 * CKP + q2 * 8];
        #pragma unroll
        for (int kh = 0; kh < 3; ++kh) {
            #pragma unroll
            for (int kw = 0; kw < 3; ++kw) {
                int tap = kh * 3 + kw;
                half8 b0 = *(const half8*)(wbase + (tap * 64 +  0) * CKP);
                half8 b1 = *(const half8*)(wbase + (tap * 64 + 32) * CKP);
                #pragma unroll
                for (int mt = 0; mt < 4; ++mt) {
                    half8 a = *(const half8*)(xbase + (kh * JW + kw + mt * 32) * CKP);
                    acc[mt][0] = __builtin_amdgcn_mfma_f32_32x32x16_f16(a, b0, acc[mt][0], 0, 0, 0);
                    acc[mt][1] = __builtin_amdgcn_mfma_f32_32x32x16_f16(a, b1, acc[mt][1], 0, 0, 0);
                }
            }
        }
    }

    int h = h0 + wave;
    #pragma unroll
    for (int nt = 0; nt < 2; ++nt) {
        int o = o0 + nt * 32 + m32;
        float fwv = wsf[64 + o];
        float scale = 1.0f / (fx * fwv);
        float bv = bias[o];
        float* op = out + (((size_t)n * 256 + o) * 128 + h) * 128;
        #pragma unroll
        for (int mt = 0; mt < 4; ++mt) {
            #pragma unroll
            for (int g = 0; g < 4; ++g) {
                int w = mt * 32 + 8 * g + 4 * q2;
                float4 r;
                r.x = fmaxf(fmaf(acc[mt][nt][4 * g + 0], scale, bv), 0.f);
                r.y = fmaxf(fmaf(acc[mt][nt][4 * g + 1], scale, bv), 0.f);
                r.z = fmaxf(fmaf(acc[mt][nt][4 * g + 2], scale, bv), 0.f);
                r.w = fmaxf(fmaf(acc[mt][nt][4 * g + 3], scale, bv), 0.f);
                *(float4*)(op + w) = r;
            }
        }
    }
}

extern "C" void kernel_launch(void* const* d_in, const int* in_sizes, int n_in,
                              void* d_out, int out_size, void* d_ws, size_t ws_size,
                              hipStream_t stream) {
    const float* x = (const float*)d_in[0];   // [16,128,128,128]
    const float* W = (const float*)d_in[1];   // [256,128,3,3]
    const float* b = (const float*)d_in[2];   // [256]
    float* out = (float*)d_out;
    float* wsf = (float*)d_ws;

    int big = (ws_size >= (size_t)XQ_OFF + XQ_BYTES) ? 1 : 0;

    hipMemsetAsync(d_ws, 0, 256, stream);     // xmax slot (ws poisoned 0xAA)
    if (big)
        hipMemsetAsync((char*)d_ws + ZP_OFF, 0, 2048, stream);   // zero page for OOB staging

    xmax_kernel<<<1024, 256, 0, stream>>>(x, (unsigned int*)d_ws, (16 * 128 * 128 * 128) / 4);
    wq_kernel<<<256, 128, 0, stream>>>(W, wsf, big);

    if (big) {
        _Float16* xq = (_Float16*)((char*)d_ws + XQ_OFF);
        quantx_kernel<<<16 * 8 * 128, 128, 0, stream>>>(x, wsf, xq);
        conv_main<<<2048, 256, 0, stream>>>(xq, b, wsf, out);
    } else {
        dim3 grid(512, 4);
        conv_fallback<<<grid, 256, 0, stream>>>(x, b, wsf, out);
    }
}

// Round 3
// 493.244 us; speedup vs baseline: 1.0157x; 1.0086x over previous
//
#include <hip/hip_runtime.h>
#include <math.h>

// Quantized ConvBlock, round 6: T3 phase-split on top of R5's T4 counted-vmcnt.
//   R2 result: removing the chunk-boundary drain alone gained little — the intra-chunk
//   schedule still phase-locked all 8 waves (read burst -> MFMA burst, pipes serial).
//   New per-chunk schedule (m201-style):
//     s_barrier; stage 10 gl_lds (chunk cc+1 -> other buf); s_waitcnt vmcnt(10); s_barrier
//     3 phases (one per kw): { 12 ds_read_b128 (6 xf + 6 wf); setprio(1); 24 MFMA;
//                              setprio(0); s_barrier }   (last phase's barrier = loop-top)
//   Waves stagger within a phase (LDS serves serially; early finishers MFMA at prio 1
//   while laggards read) -> LDS and matrix pipes overlap instead of alternating.
//
// ws layout (bytes):
//   0        : xmax bits (uint)             [memset to 0]
//   256      : fw[256] floats
//   2048     : wq_a  f16 [o][tap][c]        (fallback layout)
//   655360   : wq_b  f16 [cc][tap][o'][c16'] (bank-swizzled slots)
//   1572864  : ZP zero page (2 KB, memset)
//   2097152  : xq    f16 [n][cc][h][w][c16]

#define FW_NUM 20017.23017802413f
#define FX_NUM 835.5924988699913f
#define WQA_OFF 2048
#define WQB_OFF (640 * 1024)
#define ZP_OFF  (1536 * 1024)
#define XQ_OFF  (2 * 1024 * 1024)
#define XQ_BYTES 67108864ull

// fallback-kernel tile params (R2 kernel, kept verbatim)
#define CK  16
#define CKP 24
#define JW  130

typedef _Float16 half8 __attribute__((ext_vector_type(8)));
typedef _Float16 half4 __attribute__((ext_vector_type(4)));
typedef float floatx16 __attribute__((ext_vector_type(16)));

__device__ __forceinline__ void gl_lds16(const void* g, void* s) {
    __builtin_amdgcn_global_load_lds((const __attribute__((address_space(1))) void*)g,
                                     (__attribute__((address_space(3))) void*)s, 16, 0, 0);
}

__global__ void xmax_kernel(const float* __restrict__ x, unsigned int* wsu, int n4) {
    int tid = blockIdx.x * blockDim.x + threadIdx.x;
    int stride = gridDim.x * blockDim.x;
    const float4* x4 = (const float4*)x;
    float m = 0.f;
    for (int i = tid; i < n4; i += stride) {
        float4 v = x4[i];
        m = fmaxf(m, fmaxf(fmaxf(fabsf(v.x), fabsf(v.y)), fmaxf(fabsf(v.z), fabsf(v.w))));
    }
    #pragma unroll
    for (int off = 32; off >= 1; off >>= 1)
        m = fmaxf(m, __shfl_down(m, off, 64));
    __shared__ float sm[4];
    if ((threadIdx.x & 63) == 0) sm[threadIdx.x >> 6] = m;
    __syncthreads();
    if (threadIdx.x == 0) {
        m = fmaxf(fmaxf(sm[0], sm[1]), fmaxf(sm[2], sm[3]));
        atomicMax(wsu, __float_as_uint(m));
    }
}

// one block per o (256 blocks, 128 threads; t = input channel c)
__global__ void wq_kernel(const float* __restrict__ W, float* wsf, int big) {
    int o = blockIdx.x;
    int t = threadIdx.x;
    const float* wrow = W + o * 1152;
    float wv[9];
    float s = 0.f;
    #pragma unroll
    for (int k = 0; k < 9; k++) { wv[k] = wrow[t * 9 + k]; s += fabsf(wv[k]); }
    #pragma unroll
    for (int off = 32; off >= 1; off >>= 1) s += __shfl_down(s, off, 64);
    __shared__ float sred[2];
    __shared__ float sfw;
    if ((t & 63) == 0) sred[t >> 6] = s;
    __syncthreads();
    if (t == 0) {
        float wsum = sred[0] + sred[1];
        if (wsum == 0.f) wsum = 1.f;
        float fw = FW_NUM / wsum;
        wsf[64 + o] = fw;
        sfw = fw;
    }
    __syncthreads();
    float fw = sfw;
    _Float16* wqa = (_Float16*)((char*)wsf + WQA_OFF);   // [o][tap][c]
    _Float16* wqb = (_Float16*)((char*)wsf + WQB_OFF);   // [cc][tap][o'][c16'] swizzled slots
    // bank-swizzle slot for logical (o, half q): slot o' bits0-1 ^= o bits3-4, q' = q ^ o bit2
    int oswz = (o & ~3) | ((o & 3) ^ ((o >> 3) & 3));
    int qflip = (o >> 2) & 1;
    #pragma unroll
    for (int k = 0; k < 9; k++) {
        _Float16 hv = (_Float16)rintf(wv[k] * fw);       // rintf = RNE = jnp.round
        wqa[(o * 9 + k) * 128 + t] = hv;
        if (big) {
            int q = (t >> 3) & 1;
            int qswz = q ^ qflip;
            wqb[(((t >> 4) * 9 + k) * 256 + oswz) * 16 + qswz * 8 + (t & 7)] = hv;
        }
    }
}

// block = one (n, cc, h): quantize 16 c-planes' row h into [w][c16] (4 KB contiguous)
__global__ void quantx_kernel(const float* __restrict__ x, const float* __restrict__ wsf,
                              _Float16* __restrict__ xq) {
    int bid = blockIdx.x;           // (n*8 + cc)*128 + h
    int h  = bid & 127;
    int cc = (bid >> 7) & 7;
    int n  = bid >> 10;
    float xmax = __uint_as_float(((const unsigned int*)wsf)[0]);
    float fx = xmax > 0.f ? FX_NUM / xmax : 1.0f;
    int w = threadIdx.x;            // 128
    const float* xp = x + ((size_t)(n * 128 + cc * 16) * 128 + h) * 128 + w;
    half8 v0, v1;
    #pragma unroll
    for (int ci = 0; ci < 8; ci++)  v0[ci] = (_Float16)rintf(fx * xp[(size_t)ci * 16384]);
    #pragma unroll
    for (int ci = 8; ci < 16; ci++) v1[ci - 8] = (_Float16)rintf(fx * xp[(size_t)ci * 16384]);
    _Float16* op = xq + ((size_t)bid * 128 + w) * 16;
    *(half8*)op = v0;
    *(half8*)(op + 8) = v1;
}

__global__ __launch_bounds__(256, 2) void conv_main(const _Float16* __restrict__ xq,
                                                    const float* __restrict__ bias,
                                                    const float* __restrict__ wsf,
                                                    float* __restrict__ out) {
    // xs: 18 rows x 68 slots(16B) = 19584 B + pad -> 20480 B per buffer.
    //   row r <-> input h = h0+r-1; slot sp occupant u = sp ^ ((sp>>3)&7), j=u>>1 (w=w0+j-1), q=u&1.
    // wl: 9 taps x 64 o x 32 B = 18432 B + 1024 pad -> 19456 B per buffer.
    __shared__ __align__(16) _Float16 xs[2][10240];   // 40960 B
    __shared__ __align__(16) _Float16 wl[2][9728];    // 38912 B
    __shared__ float sc[64], bz[64];                  // total 80384 B -> 2 blk/CU

    float xmax = __uint_as_float(((const unsigned int*)wsf)[0]);
    float fx = xmax > 0.f ? FX_NUM / xmax : 1.0f;

    // XCD-contiguous remap (2048 % 8 == 0 -> bijective)
    int bx0 = blockIdx.x;
    int bx = (bx0 & 7) * 256 + (bx0 >> 3);
    int o0 = (bx & 3) << 6;
    int w0 = ((bx >> 2) & 3) << 5;
    int h0 = ((bx >> 4) & 7) << 4;
    int n  = bx >> 7;

    int tid = threadIdx.x;
    int lane = tid & 63;
    int wv = tid >> 6;
    int m32 = lane & 31;
    int q2 = lane >> 5;

    const char* wsb = (const char*)wsf;

    // ---- swizzled read column offsets (bytes within a row / tap block)
    int xcol[3];
    #pragma unroll
    for (int kw = 0; kw < 3; ++kw) {
        int j = m32 + kw;
        xcol[kw] = (j * 32 + q2 * 16) ^ ((((j) >> 2) & 7) << 4);
    }
    int wcol = (m32 * 32 + q2 * 16) ^ (((m32 >> 2) & 7) << 4);

    // ---- per-wave staging slots: s = wv + 4k, k = 0..9 (40 slots: 20 x, 18 w, 2 dummy)
    //   sources as 32-bit offsets from ws base; OOB -> zero page; stride advances per chunk.
    int goff[10];
    int gstr[10];
    #pragma unroll
    for (int k = 0; k < 10; ++k) {
        int s = wv + 4 * k;
        int off, str;
        if (s < 20) {
            int slot = s * 64 + lane;
            int r = (slot * 241) >> 14;          // exact /68 for slot < 1224
            int spi = slot - r * 68;
            int u = spi ^ ((spi >> 3) & 7);      // involution: slot -> occupant
            int j = u >> 1, q = u & 1;
            int h = h0 + r - 1, w = w0 + j - 1;
            bool ok = (slot < 1224) && (h >= 0) && (h < 128) && (w >= 0) && (w < 128);
            if (ok) {
                off = XQ_OFF + n * 4194304 + (h * 128 + w) * 32 + q * 16;
                str = 524288;                    // next c-chunk plane
            } else {
                off = ZP_OFF + lane * 16;
                str = 0;
            }
        } else if (s < 38) {
            int t2 = s - 20, tap = t2 >> 1, g = t2 & 1;
            off = WQB_OFF + (tap * 256 + o0) * 32 + g * 1024 + lane * 16;
            str = 73728;                         // next c-chunk of wq_b
        } else {
            off = ZP_OFF + lane * 16;            // dummy (keeps vmcnt count uniform)
            str = 0;
        }
        goff[k] = off;
        gstr[k] = str;
    }

    auto stage = [&](int tb) {
        #pragma unroll
        for (int k = 0; k < 10; ++k) {
            int s = wv + 4 * k;
            char* dst;
            if (s < 20)      dst = (char*)&xs[tb][0] + s * 1024;
            else if (s < 38) dst = (char*)&wl[tb][0] + (s - 20) * 1024;
            else             dst = (char*)&wl[tb][0] + 18 * 1024;     // pad
            gl_lds16(wsb + goff[k], dst);
            goff[k] += gstr[k];
        }
    };

    // ---- init: scale/bias to LDS (before any staging; trivial drain)
    if (tid < 64) {
        float fwv = wsf[64 + o0 + tid];
        sc[tid] = 1.0f / (fx * fwv);
        bz[tid] = bias[o0 + tid];
    }
    __syncthreads();

    floatx16 acc[2][4];
    #pragma unroll
    for (int a1 = 0; a1 < 2; a1++)
        #pragma unroll
        for (int a2 = 0; a2 < 4; a2++)
            #pragma unroll
            for (int e = 0; e < 16; e++) acc[a1][a2][e] = 0.f;

    // ---- prologue: stage chunk 0 into buffer 0 (stays in flight through barrier #1)
    stage(0);

    // ---- K loop: 8 chunks of 16 c; T4 chunk boundary + T3 3-phase compute
    for (int cc = 0; cc < 8; ++cc) {
        int cb = cc & 1;
        __builtin_amdgcn_s_barrier();            // all waves done reading buf cb^1
        if (cc < 7) {
            stage(cb ^ 1);                       // 10 loads: chunk cc+1 -> other buffer
            asm volatile("s_waitcnt vmcnt(10)" ::: "memory");   // chunk cc's loads retired
        } else {
            asm volatile("s_waitcnt vmcnt(0)" ::: "memory");
        }
        __builtin_amdgcn_s_barrier();            // buf cb valid for everyone

        const char* xb = (const char*)&xs[cb][0] + wv * (4 * 1088);
        const char* wb = (const char*)&wl[cb][0];
        #pragma unroll
        for (int kw = 0; kw < 3; ++kw) {
            // phase kw: 12 ds_read_b128, then one pure-MFMA cluster, then phase fence
            half8 xf[6];
            #pragma unroll
            for (int srow = 0; srow < 6; ++srow)
                xf[srow] = *(const half8*)(xb + srow * 1088 + xcol[kw]);
            half8 wf[6];
            #pragma unroll
            for (int kh = 0; kh < 3; ++kh) {
                const char* wp = wb + (kh * 3 + kw) * 2048 + wcol;
                wf[kh * 2]     = *(const half8*)wp;
                wf[kh * 2 + 1] = *(const half8*)(wp + 1024);
            }
            __builtin_amdgcn_s_setprio(1);
            #pragma unroll
            for (int kh = 0; kh < 3; ++kh) {
                #pragma unroll
                for (int p = 0; p < 4; ++p) {
                    acc[0][p] = __builtin_amdgcn_mfma_f32_32x32x16_f16(wf[kh * 2],     xf[p + kh], acc[0][p], 0, 0, 0);
                    acc[1][p] = __builtin_amdgcn_mfma_f32_32x32x16_f16(wf[kh * 2 + 1], xf[p + kh], acc[1][p], 0, 0, 0);
                }
            }
            __builtin_amdgcn_s_setprio(0);
            if (kw < 2) __builtin_amdgcn_s_barrier();   // phase fence (last = loop-top barrier)
        }
    }

    // ---- epilogue: D row = o (reg), col = pixel (lane) -> coalesced stores
    #pragma unroll
    for (int ot = 0; ot < 2; ++ot) {
        #pragma unroll
        for (int e = 0; e < 16; ++e) {
            int o_loc = ot * 32 + (e & 3) + 8 * (e >> 2) + 4 * q2;
            float scale = sc[o_loc];
            float bv = bz[o_loc];
            #pragma unroll
            for (int p = 0; p < 4; ++p) {
                int h = h0 + wv * 4 + p;
                float v = fmaxf(fmaf(acc[ot][p][e], scale, bv), 0.f);
                out[(((size_t)(n * 256 + o0 + o_loc)) * 128 + h) * 128 + w0 + m32] = v;
            }
        }
    }
}

// ---------------- fallback (R2 kernel, used if ws too small) ----------------
__global__ __launch_bounds__(256, 2) void conv_fallback(const float* __restrict__ x,
                                                        const float* __restrict__ bias,
                                                        const float* __restrict__ wsf,
                                                        float* __restrict__ out) {
    __shared__ __align__(16) _Float16 xs[6 * JW * CKP];
    __shared__ __align__(16) _Float16 wlds[9 * 64 * CKP];

    const unsigned int* wsu = (const unsigned int*)wsf;
    float xmax = __uint_as_float(wsu[0]);
    float fx = xmax > 0.f ? FX_NUM / xmax : 1.0f;

    int bx = blockIdx.x;
    int n  = bx >> 5;
    int h0 = (bx & 31) << 2;
    int o0 = blockIdx.y << 6;

    int tid  = threadIdx.x;
    int lane = tid & 63;
    int wave = tid >> 6;
    int m32  = lane & 31;
    int q2   = lane >> 5;

    const _Float16* wq16 = (const _Float16*)((const char*)wsf + WQA_OFF);
    const float* xn = x + (size_t)n * (128 * 128 * 128);

    floatx16 acc[4][2];
    #pragma unroll
    for (int mt = 0; mt < 4; mt++)
        #pragma unroll
        for (int nt = 0; nt < 2; nt++)
            #pragma unroll
            for (int e = 0; e < 16; e++) acc[mt][nt][e] = 0.f;

    if (tid < 192) {
        int r = tid >> 5;
        int s = tid & 31;
        int c = s & 15;
        int j = (s >> 4) ? (JW - 1) : 0;
        xs[(r * JW + j) * CKP + c] = (_Float16)0.f;
    }

    for (int c0 = 0; c0 < 128; c0 += CK) {
        __syncthreads();
        #pragma unroll
        for (int it = 0; it < 12; ++it) {
            int idx = tid + it * 256;
            int j  = (idx & 127) + 1;
            int c4 = (idx >> 7) & 3;
            int r  = idx >> 9;
            int h  = h0 + r - 1;
            float v0 = 0.f, v1 = 0.f, v2 = 0.f, v3 = 0.f;
            if (h >= 0 && h < 128) {
                const float* xp = xn + (size_t)(c0 + c4 * 4) * 16384 + h * 128 + (j - 1);
                v0 = xp[0]; v1 = xp[16384]; v2 = xp[32768]; v3 = xp[49152];
            }
            half4 hv;
            hv[0] = (_Float16)rintf(fx * v0);
            hv[1] = (_Float16)rintf(fx * v1);
            hv[2] = (_Float16)rintf(fx * v2);
            hv[3] = (_Float16)rintf(fx * v3);
            *(half4*)&xs[(r * JW + j) * CKP + c4 * 4] = hv;
        }
        #pragma unroll
        for (int it = 0; it < 5; ++it) {
            int idx = tid + it * 256;
            if (idx < 1152) {
                int o   = idx / 18;
                int rem = idx - o * 18;
                int tap = rem >> 1;
                int g   = rem & 1;
                half8 v = *(const half8*)(wq16 + ((size_t)(o0 + o) * 9 + tap) * 128 + c0 + g * 8);
                *(half8*)&wlds[(tap * 64 + o) * CKP + g * 8] = v;
            }
        }
        __syncthreads();

        const _Float16* xbase = &xs[(wave * JW + m32) * CKP + q2 * 8];
        const _Float16* wbase = &wlds[m32 * CKP + q2 * 8];
        #pragma unroll
        for (int kh = 0; kh < 3; ++kh) {
            #pragma unroll
            for (int kw = 0; kw < 3; ++kw) {
                int tap = kh * 3 + kw;
                half8 b0 = *(const half8*)(wbase + (tap * 64 +  0) * CKP);
                half8 b1 = *(const half8*)(wbase + (tap * 64 + 32) * CKP);
                #pragma unroll
                for (int mt = 0; mt < 4; ++mt) {
                    half8 a = *(const half8*)(xbase + (kh * JW + kw + mt * 32) * CKP);
                    acc[mt][0] = __builtin_amdgcn_mfma_f32_32x32x16_f16(a, b0, acc[mt][0], 0, 0, 0);
                    acc[mt][1] = __builtin_amdgcn_mfma_f32_32x32x16_f16(a, b1, acc[mt][1], 0, 0, 0);
                }
            }
        }
    }

    int h = h0 + wave;
    #pragma unroll
    for (int nt = 0; nt < 2; ++nt) {
        int o = o0 + nt * 32 + m32;
        float fwv = wsf[64 + o];
        float scale = 1.0f / (fx * fwv);
        float bv = bias[o];
        float* op = out + (((size_t)n * 256 + o) * 128 + h) * 128;
        #pragma unroll
        for (int mt = 0; mt < 4; ++mt) {
            #pragma unroll
            for (int g = 0; g < 4; ++g) {
                int w = mt * 32 + 8 * g + 4 * q2;
                float4 r;
                r.x = fmaxf(fmaf(acc[mt][nt][4 * g + 0], scale, bv), 0.f);
                r.y = fmaxf(fmaf(acc[mt][nt][4 * g + 1], scale, bv), 0.f);
                r.z = fmaxf(fmaf(acc[mt][nt][4 * g + 2], scale, bv), 0.f);
                r.w = fmaxf(fmaf(acc[mt][nt][4 * g + 3], scale, bv), 0.f);
                *(float4*)(op + w) = r;
            }
        }
    }
}

extern "C" void kernel_launch(void* const* d_in, const int* in_sizes, int n_in,
                              void* d_out, int out_size, void* d_ws, size_t ws_size,
                              hipStream_t stream) {
    const float* x = (const float*)d_in[0];   // [16,128,128,128]
    const float* W = (const float*)d_in[1];   // [256,128,3,3]
    const float* b = (const float*)d_in[2];   // [256]
    float* out = (float*)d_out;
    float* wsf = (float*)d_ws;

    int big = (ws_size >= (size_t)XQ_OFF + XQ_BYTES) ? 1 : 0;

    hipMemsetAsync(d_ws, 0, 256, stream);     // xmax slot (ws poisoned 0xAA)
    if (big)
        hipMemsetAsync((char*)d_ws + ZP_OFF, 0, 2048, stream);   // zero page for OOB staging

    xmax_kernel<<<1024, 256, 0, stream>>>(x, (unsigned int*)d_ws, (16 * 128 * 128 * 128) / 4);
    wq_kernel<<<256, 128, 0, stream>>>(W, wsf, big);

    if (big) {
        _Float16* xq = (_Float16*)((char*)d_ws + XQ_OFF);
        quantx_kernel<<<16 * 8 * 128, 128, 0, stream>>>(x, wsf, xq);
        conv_main<<<2048, 256, 0, stream>>>(xq, b, wsf, out);
    } else {
        dim3 grid(512, 4);
        conv_fallback<<<grid, 256, 0, stream>>>(x, b, wsf, out);
    }
}